// Round 3
// baseline (630.930 us; speedup 1.0000x reference)
//
#include <hip/hip_runtime.h>

// SpecialSpmm: out[i] = sum_{e: row_e == i} values[e] * b[col_e]
// N = 100000, E = 1600000, D = 128.
//
// Pipeline:
//   1. hist_buckets:  count edges per 64-row bucket (1563 buckets)
//   2. scan_buckets:  single-block exclusive scan -> bucket offsets + cursors
//   3. binscatter:    scatter packed (lrow|col, val) into bucket regions
//                     (write working set ~1563 lines -> L2-resident, no thrash)
//   4. sortgather:    per bucket: LDS counting-sort by row, then 8 lane-groups
//                     register-accumulate 8 rows each, coalesced float4 store.
//
// d_in[0] = values (E f32), d_in[1] = b (N*D f32),
// d_in[2] = indices (2*E i32: rows then cols), d_in[3] = n (1 i32).

#define D_DIM   128
#define RPB     64        // rows per bucket (row >> 6)
#define CAP     2048      // max edges staged per chunk (mean 1024, sd ~32)
#define COLBITS 17        // N <= 131072

// ---------------- 1: bucket histogram ----------------
__global__ void hist_buckets(const int* __restrict__ indices, int* __restrict__ bcnt, int E) {
    int stride = gridDim.x * blockDim.x;
    for (int e = blockIdx.x * blockDim.x + threadIdx.x; e < E; e += stride)
        atomicAdd(&bcnt[indices[e] >> 6], 1);
}

// ---------------- 2: single-block exclusive scan (n <= 2048) ----------------
__global__ void scan_buckets(int* __restrict__ cnt /*in: counts, out: cursors*/,
                             int* __restrict__ boff, int n) {
    __shared__ int s[256];
    int t = threadIdx.x;
    int base = t * 8;
    int loc[8];
    int tot = 0;
#pragma unroll
    for (int k = 0; k < 8; ++k) {
        int i = base + k;
        loc[k] = (i < n) ? cnt[i] : 0;
        tot += loc[k];
    }
    s[t] = tot;
    __syncthreads();
    for (int ofs = 1; ofs < 256; ofs <<= 1) {
        int v = (t >= ofs) ? s[t - ofs] : 0;
        __syncthreads();
        s[t] += v;
        __syncthreads();
    }
    int run = s[t] - tot;  // exclusive prefix of this thread's chunk
#pragma unroll
    for (int k = 0; k < 8; ++k) {
        int i = base + k;
        if (i < n) { boff[i] = run; cnt[i] = run; }
        run += loc[k];
    }
    if (t == 255) boff[n] = s[255];
}

// ---------------- 3: scatter edges into bucket regions ----------------
__global__ void binscatter(const int* __restrict__ indices, const float* __restrict__ values,
                           int* __restrict__ cursor, int2* __restrict__ cv, int E) {
    int stride = gridDim.x * blockDim.x;
    for (int e = blockIdx.x * blockDim.x + threadIdx.x; e < E; e += stride) {
        int row = indices[e];
        int col = indices[E + e];
        float v = values[e];
        int pos = atomicAdd(&cursor[row >> 6], 1);
        cv[pos] = make_int2(((row & (RPB - 1)) << COLBITS) | col, __float_as_int(v));
    }
}

// ---------------- 4: fused per-bucket counting-sort + gather ----------------
__global__ __launch_bounds__(256) void sortgather(const float* __restrict__ b,
                                                  const int* __restrict__ boff,
                                                  const int2* __restrict__ cv,
                                                  float* __restrict__ out, int N) {
    __shared__ int2 sorted[CAP];
    __shared__ int rcnt[RPB];
    __shared__ int roff[RPB];
    __shared__ int rcur[RPB];

    int tid  = threadIdx.x;
    int lane = tid & 31;
    int grp  = tid >> 5;            // 8 groups of 32 lanes
    int bucket  = blockIdx.x;
    int rowbase = bucket << 6;
    int s = boff[bucket];
    int e = boff[bucket + 1];

    float4 acc[8];
#pragma unroll
    for (int r = 0; r < 8; ++r) acc[r] = make_float4(0.f, 0.f, 0.f, 0.f);

    for (int base = s; base < e; base += CAP) {
        int cnt = min(e - base, CAP);

        if (tid < RPB) rcnt[tid] = 0;
        __syncthreads();

        // histogram rows of this chunk (LDS atomics)
        for (int i = tid; i < cnt; i += 256)
            atomicAdd(&rcnt[cv[base + i].x >> COLBITS], 1);
        __syncthreads();

        // wave-scan the 64 row counts (wave 0 only)
        if (tid < RPB) {
            int c = rcnt[tid];
            int v = c;
            for (int d = 1; d < RPB; d <<= 1) {
                int t = __shfl_up(v, d, 64);
                if (tid >= d) v += t;
            }
            roff[tid] = v - c;
            rcur[tid] = v - c;
        }
        __syncthreads();

        // counting-sort chunk into LDS by local row
        for (int i = tid; i < cnt; i += 256) {
            int2 p = cv[base + i];
            int pos = atomicAdd(&rcur[p.x >> COLBITS], 1);
            sorted[pos] = p;
        }
        __syncthreads();

        // gather: group g accumulates rows g*8 .. g*8+7
#pragma unroll
        for (int r = 0; r < 8; ++r) {
            int lr = (grp << 3) | r;
            int i  = roff[lr];
            int re = rcur[lr];
            for (; i + 1 < re; i += 2) {
                int2 p0 = sorted[i];
                int2 p1 = sorted[i + 1];
                float v0 = __int_as_float(p0.y);
                float v1 = __int_as_float(p1.y);
                const float4 b0 = *reinterpret_cast<const float4*>(
                    b + (long long)(p0.x & ((1 << COLBITS) - 1)) * D_DIM + (lane << 2));
                const float4 b1 = *reinterpret_cast<const float4*>(
                    b + (long long)(p1.x & ((1 << COLBITS) - 1)) * D_DIM + (lane << 2));
                acc[r].x += v0 * b0.x; acc[r].y += v0 * b0.y;
                acc[r].z += v0 * b0.z; acc[r].w += v0 * b0.w;
                acc[r].x += v1 * b1.x; acc[r].y += v1 * b1.y;
                acc[r].z += v1 * b1.z; acc[r].w += v1 * b1.w;
            }
            if (i < re) {
                int2 p0 = sorted[i];
                float v0 = __int_as_float(p0.y);
                const float4 b0 = *reinterpret_cast<const float4*>(
                    b + (long long)(p0.x & ((1 << COLBITS) - 1)) * D_DIM + (lane << 2));
                acc[r].x += v0 * b0.x; acc[r].y += v0 * b0.y;
                acc[r].z += v0 * b0.z; acc[r].w += v0 * b0.w;
            }
        }
        __syncthreads();   // protect sorted[] before next chunk
    }

    // one coalesced 512B store per row (also zeros empty rows)
#pragma unroll
    for (int r = 0; r < 8; ++r) {
        int row = rowbase + (grp << 3) + r;
        if (row < N)
            *reinterpret_cast<float4*>(out + (long long)row * D_DIM + (lane << 2)) = acc[r];
    }
}

// ---------------- fallback: atomic scatter ----------------
__global__ void spmm_atomic_scatter(const float* __restrict__ values,
                                    const float* __restrict__ b,
                                    const int* __restrict__ indices,
                                    float* __restrict__ out, int E) {
    long long gid = (long long)blockIdx.x * blockDim.x + threadIdx.x;
    long long total = (long long)E * 32;
    if (gid >= total) return;
    int e = (int)(gid >> 5);
    int c = (int)(gid & 31);
    int row = indices[e];
    int col = indices[E + e];
    float v = values[e];
    const float4 bv = *reinterpret_cast<const float4*>(b + (long long)col * D_DIM + (c << 2));
    float* o = out + (long long)row * D_DIM + (c << 2);
    atomicAdd(o + 0, v * bv.x);
    atomicAdd(o + 1, v * bv.y);
    atomicAdd(o + 2, v * bv.z);
    atomicAdd(o + 3, v * bv.w);
}

extern "C" void kernel_launch(void* const* d_in, const int* in_sizes, int n_in,
                              void* d_out, int out_size, void* d_ws, size_t ws_size,
                              hipStream_t stream) {
    const float* values = (const float*)d_in[0];
    const float* b      = (const float*)d_in[1];
    const int*   idx    = (const int*)d_in[2];
    float*       out    = (float*)d_out;

    const int E  = in_sizes[0];
    const int N  = out_size / D_DIM;
    const int NB = (N + RPB - 1) / RPB;    // buckets of 64 rows

    // Workspace: boff (NB+1) | bcur (NB) | cv (E int2)
    size_t need = ((size_t)(NB + 1) + NB + 2 * (size_t)E) * sizeof(int);
    if (ws_size < need || N > (1 << COLBITS) || NB > 2048) {
        hipMemsetAsync(d_out, 0, (size_t)out_size * sizeof(float), stream);
        long long total = (long long)E * 32;
        int block = 256;
        long long grid = (total + block - 1) / block;
        spmm_atomic_scatter<<<(int)grid, block, 0, stream>>>(values, b, idx, out, E);
        return;
    }

    int*  boff = (int*)d_ws;
    int*  bcur = boff + (NB + 1);
    int2* cv   = (int2*)(bcur + NB);

    hipMemsetAsync(bcur, 0, (size_t)NB * sizeof(int), stream);
    hist_buckets<<<2048, 256, 0, stream>>>(idx, bcur, E);
    scan_buckets<<<1, 256, 0, stream>>>(bcur, boff, NB);
    binscatter<<<2048, 256, 0, stream>>>(idx, values, bcur, cv, E);
    sortgather<<<NB, 256, 0, stream>>>(b, boff, cv, out, N);
}

// Round 4
// 176.420 us; speedup vs baseline: 3.5763x; 3.5763x over previous
//
#include <hip/hip_runtime.h>

// SpecialSpmm: out[i] = sum_{e: row_e == i} values[e] * b[col_e]
// N = 100000, E = 1600000, D = 128.
//
// Zero-global-atomic pipeline:
//   1. chunk_sort:  per 8192-edge chunk: LDS counting-sort by 64-row bucket,
//                   stream sorted payload out sequentially (full-line writes),
//                   emit per-chunk run-start table rs[chunk][bucket] (u16).
//   2. sortgather2: per bucket: collect the chunk-runs into LDS, counting-sort
//                   by row, register-gather b rows (8 groups x 8 rows x float4),
//                   one coalesced 512B store per row.
//
// d_in[0] = values (E f32), d_in[1] = b (N*D f32),
// d_in[2] = indices (2*E i32: rows then cols), d_in[3] = n (1 i32).

#define D_DIM    128
#define RPB      64                    // rows per bucket
#define COLBITS  17                    // N <= 131072
#define COLMASK  ((1 << COLBITS) - 1)
#define CHUNK    8192                  // edges per sort chunk
#define NCMAX    256                   // max chunks (E <= 2M)
#define NBMAX    1600                  // max buckets (N <= 102400)
#define CAP      2048                  // LDS staging capacity (records)

// ---------------- 1: per-chunk LDS counting sort ----------------
__global__ __launch_bounds__(256) void chunk_sort(
    const int* __restrict__ idx, const float* __restrict__ values,
    int2* __restrict__ cv, unsigned short* __restrict__ rs_g,
    int E, int NBUX) {
    __shared__ int  hist[NBMAX];
    __shared__ int  cur[NBMAX];
    __shared__ int  partial[256];
    __shared__ int2 payload[CHUNK];

    int tid  = threadIdx.x;
    int base = blockIdx.x * CHUNK;
    int cnt  = min(CHUNK, E - base);

    for (int i = tid; i < NBUX; i += 256) hist[i] = 0;
    __syncthreads();

    for (int i = tid; i < cnt; i += 256)
        atomicAdd(&hist[idx[base + i] >> 6], 1);
    __syncthreads();

    // block-wide exclusive scan over NBUX (<= 2048 = 256 threads x 8 cells)
    int loc[8];
    int tot = 0;
#pragma unroll
    for (int k = 0; k < 8; ++k) {
        int i = tid * 8 + k;
        loc[k] = (i < NBUX) ? hist[i] : 0;
        tot += loc[k];
    }
    partial[tid] = tot;
    __syncthreads();
    for (int ofs = 1; ofs < 256; ofs <<= 1) {
        int v = (tid >= ofs) ? partial[tid - ofs] : 0;
        __syncthreads();
        partial[tid] += v;
        __syncthreads();
    }
    int run = partial[tid] - tot;
#pragma unroll
    for (int k = 0; k < 8; ++k) {
        int i = tid * 8 + k;
        if (i < NBUX) {
            cur[i] = run;
            rs_g[(size_t)blockIdx.x * NBUX + i] = (unsigned short)run;
        }
        run += loc[k];
    }
    __syncthreads();

    // LDS scatter into bucket-sorted payload
    for (int i = tid; i < cnt; i += 256) {
        int   row = idx[base + i];
        int   col = idx[E + base + i];
        float v   = values[base + i];
        int pos = atomicAdd(&cur[row >> 6], 1);
        payload[pos] = make_int2(((row & (RPB - 1)) << COLBITS) | col,
                                 __float_as_int(v));
    }
    __syncthreads();

    // sequential full-line streaming write-out
    for (int i = tid; i < cnt; i += 256) cv[base + i] = payload[i];
}

// ---------------- 2: per-bucket collect + row-sort + gather ----------------
__global__ __launch_bounds__(256) void sortgather2(
    const float* __restrict__ b, const int2* __restrict__ cv,
    const unsigned short* __restrict__ rs_g, float* __restrict__ out,
    int N, int E, int NCHUNK, int NBUX) {
    __shared__ int2 stage[CAP];
    __shared__ int2 sorted[CAP];
    __shared__ int  runsS[NCMAX];      // global cv index of each chunk-run start
    __shared__ int  dstS[NCMAX + 1];   // exclusive prefix of run counts
    __shared__ int  rcnt[RPB], roff[RPB], rcur[RPB];
    __shared__ int  sWin[2];
    __shared__ int  sTot;

    int tid  = threadIdx.x;
    int lane = tid & 31;
    int grp  = tid >> 5;               // 8 groups of 32 lanes
    int k    = blockIdx.x;             // bucket id

    // per-chunk run locations for this bucket
    for (int c = tid; c < NCHUNK; c += 256) {
        int cbase = c * CHUNK;
        int ccnt  = min(CHUNK, E - cbase);
        int s = rs_g[(size_t)c * NBUX + k];
        int e = (k + 1 < NBUX) ? (int)rs_g[(size_t)c * NBUX + k + 1] : ccnt;
        runsS[c] = cbase + s;
        dstS[c]  = e - s;              // run count (prefix built next)
    }
    __syncthreads();

    // exclusive scan over NCHUNK run counts (wave 0, 4 cells/lane)
    if (tid < 64) {
        int c0 = tid * 4;
        int l0 = (c0 + 0 < NCHUNK) ? dstS[c0 + 0] : 0;
        int l1 = (c0 + 1 < NCHUNK) ? dstS[c0 + 1] : 0;
        int l2 = (c0 + 2 < NCHUNK) ? dstS[c0 + 2] : 0;
        int l3 = (c0 + 3 < NCHUNK) ? dstS[c0 + 3] : 0;
        int sum = l0 + l1 + l2 + l3;
        int v = sum;
#pragma unroll
        for (int d = 1; d < 64; d <<= 1) {
            int t = __shfl_up(v, d, 64);
            if (tid >= d) v += t;
        }
        int run = v - sum;
        dstS[c0 + 0] = run; run += l0;
        dstS[c0 + 1] = run; run += l1;
        dstS[c0 + 2] = run; run += l2;
        dstS[c0 + 3] = run;
        if (tid == 63) sTot = v;
    }
    __syncthreads();
    if (tid == 0) dstS[NCHUNK] = sTot;

    float4 acc[8];
#pragma unroll
    for (int r = 0; r < 8; ++r) acc[r] = make_float4(0.f, 0.f, 0.f, 0.f);

    int cdone = 0;
    while (cdone < NCHUNK) {
        __syncthreads();               // stage/sorted reuse + sWin publish
        if (tid == 0) {
            int startrec = dstS[cdone];
            int c = cdone;
            while (c < NCHUNK && dstS[c + 1] - startrec <= CAP) ++c;
            if (c == cdone) c = cdone + 1;   // pathological; unreachable for valid data
            sWin[0] = c;
            sWin[1] = startrec;
        }
        __syncthreads();
        int cend  = sWin[0];
        int rbase = sWin[1];
        int wtot  = dstS[cend] - rbase;
        if (wtot > CAP) wtot = CAP;    // safety clamp

        // collect runs into LDS staging (thread per chunk-run)
        for (int c = cdone + tid; c < cend; c += 256) {
            int n   = dstS[c + 1] - dstS[c];
            int src = runsS[c];
            int d   = dstS[c] - rbase;
            if (n > CAP - d) n = CAP - d;    // safety clamp
            for (int j = 0; j < n; ++j) stage[d + j] = cv[src + j];
        }
        if (tid < RPB) rcnt[tid] = 0;
        __syncthreads();

        // row histogram
        for (int r = tid; r < wtot; r += 256)
            atomicAdd(&rcnt[stage[r].x >> COLBITS], 1);
        __syncthreads();

        // wave-scan 64 row counts
        if (tid < 64) {
            int cval = rcnt[tid];
            int v = cval;
#pragma unroll
            for (int d = 1; d < 64; d <<= 1) {
                int t = __shfl_up(v, d, 64);
                if (tid >= d) v += t;
            }
            roff[tid] = v - cval;
            rcur[tid] = v - cval;
        }
        __syncthreads();

        // counting-scatter by row
        for (int r = tid; r < wtot; r += 256) {
            int2 p = stage[r];
            int pos = atomicAdd(&rcur[p.x >> COLBITS], 1);
            sorted[pos] = p;
        }
        __syncthreads();

        // gather: group g accumulates rows g*8 .. g*8+7
#pragma unroll
        for (int r = 0; r < 8; ++r) {
            int lr = (grp << 3) | r;
            int i  = roff[lr];
            int re = rcur[lr];
            for (; i + 1 < re; i += 2) {
                int2 p0 = sorted[i];
                int2 p1 = sorted[i + 1];
                float v0 = __int_as_float(p0.y);
                float v1 = __int_as_float(p1.y);
                const float4 b0 = *reinterpret_cast<const float4*>(
                    b + (size_t)(p0.x & COLMASK) * D_DIM + (lane << 2));
                const float4 b1 = *reinterpret_cast<const float4*>(
                    b + (size_t)(p1.x & COLMASK) * D_DIM + (lane << 2));
                acc[r].x += v0 * b0.x; acc[r].y += v0 * b0.y;
                acc[r].z += v0 * b0.z; acc[r].w += v0 * b0.w;
                acc[r].x += v1 * b1.x; acc[r].y += v1 * b1.y;
                acc[r].z += v1 * b1.z; acc[r].w += v1 * b1.w;
            }
            if (i < re) {
                int2 p0 = sorted[i];
                float v0 = __int_as_float(p0.y);
                const float4 b0 = *reinterpret_cast<const float4*>(
                    b + (size_t)(p0.x & COLMASK) * D_DIM + (lane << 2));
                acc[r].x += v0 * b0.x; acc[r].y += v0 * b0.y;
                acc[r].z += v0 * b0.z; acc[r].w += v0 * b0.w;
            }
        }
        cdone = cend;
    }

    // one coalesced 512B store per row (also zeros empty rows)
#pragma unroll
    for (int r = 0; r < 8; ++r) {
        int row = (k << 6) + (grp << 3) + r;
        if (row < N)
            *reinterpret_cast<float4*>(out + (size_t)row * D_DIM + (lane << 2)) = acc[r];
    }
}

// ---------------- fallback: atomic scatter ----------------
__global__ void spmm_atomic_scatter(const float* __restrict__ values,
                                    const float* __restrict__ b,
                                    const int* __restrict__ indices,
                                    float* __restrict__ out, int E) {
    long long gid = (long long)blockIdx.x * blockDim.x + threadIdx.x;
    long long total = (long long)E * 32;
    if (gid >= total) return;
    int e = (int)(gid >> 5);
    int c = (int)(gid & 31);
    int row = indices[e];
    int col = indices[E + e];
    float v = values[e];
    const float4 bv = *reinterpret_cast<const float4*>(b + (long long)col * D_DIM + (c << 2));
    float* o = out + (long long)row * D_DIM + (c << 2);
    atomicAdd(o + 0, v * bv.x);
    atomicAdd(o + 1, v * bv.y);
    atomicAdd(o + 2, v * bv.z);
    atomicAdd(o + 3, v * bv.w);
}

extern "C" void kernel_launch(void* const* d_in, const int* in_sizes, int n_in,
                              void* d_out, int out_size, void* d_ws, size_t ws_size,
                              hipStream_t stream) {
    const float* values = (const float*)d_in[0];
    const float* b      = (const float*)d_in[1];
    const int*   idx    = (const int*)d_in[2];
    float*       out    = (float*)d_out;

    const int E      = in_sizes[0];
    const int N      = out_size / D_DIM;
    const int NBUX   = (N + RPB - 1) / RPB;
    const int NCHUNK = (E + CHUNK - 1) / CHUNK;

    size_t cv_bytes = (size_t)E * sizeof(int2);
    size_t rs_bytes = (size_t)NCHUNK * NBUX * sizeof(unsigned short);
    size_t need     = cv_bytes + rs_bytes;

    if (ws_size < need || NBUX > NBMAX || NCHUNK > NCMAX || N > (1 << COLBITS)) {
        hipMemsetAsync(d_out, 0, (size_t)out_size * sizeof(float), stream);
        long long total = (long long)E * 32;
        int block = 256;
        long long grid = (total + block - 1) / block;
        spmm_atomic_scatter<<<(int)grid, block, 0, stream>>>(values, b, idx, out, E);
        return;
    }

    int2*           cv   = (int2*)d_ws;
    unsigned short* rs_g = (unsigned short*)((char*)d_ws + cv_bytes);

    chunk_sort<<<NCHUNK, 256, 0, stream>>>(idx, values, cv, rs_g, E, NBUX);
    sortgather2<<<NBUX, 256, 0, stream>>>(b, cv, rs_g, out, N, E, NCHUNK, NBUX);
}